// Round 9
// baseline (116.775 us; speedup 1.0000x reference)
//
#include <hip/hip_runtime.h>
#include <hip/hip_fp16.h>
#include <math.h>

#define DIMN 128
#define KXN  65
#define NBATCH 8
#define NOPT 125

// ============ wave-level 128-point FFT (radix-2 DIF, 2 points/lane) ==========
__device__ __forceinline__ void fft_twiddles(float sigma, int lane,
                                             float* twr, float* twi){
  const float W = 0.04908738521234052f;   // 2*pi/128
  float s, c;
  sincosf(sigma * W * (float)lane, &s, &c);
  twr[0] = c; twi[0] = s;
#pragma unroll
  for (int st = 1; st <= 6; ++st){
    int off = 64 >> st;
    int m = (lane & (off - 1)) << st;
    sincosf(sigma * W * (float)m, &s, &c);
    bool hi = (lane & off) != 0;
    twr[st] = hi ? c : 1.f;
    twi[st] = hi ? s : 0.f;
  }
}

__device__ __forceinline__ void wave_fft128(float& Ar, float& Ai, float& Br, float& Bi,
                                            const float* twr, const float* twi, int lane){
  {
    float dr = Ar - Br, di = Ai - Bi;
    Ar += Br; Ai += Bi;
    float nr = dr*twr[0] - di*twi[0];
    Bi = dr*twi[0] + di*twr[0];
    Br = nr;
  }
#pragma unroll
  for (int s = 1; s <= 6; ++s){
    int off = 64 >> s;
    float sgn = (lane & off) ? -1.f : 1.f;
    float pr = __shfl_xor(Ar, off, 64);
    float pi = __shfl_xor(Ai, off, 64);
    float dr = fmaf(Ar, sgn, pr);
    float di = fmaf(Ai, sgn, pi);
    Ar = dr*twr[s] - di*twi[s];
    Ai = dr*twi[s] + di*twr[s];
    pr = __shfl_xor(Br, off, 64);
    pi = __shfl_xor(Bi, off, 64);
    dr = fmaf(Br, sgn, pr);
    di = fmaf(Bi, sgn, pi);
    Br = dr*twr[s] - di*twi[s];
    Bi = dr*twi[s] + di*twr[s];
  }
}

__device__ __forceinline__ int bitrev7(int lane){
  return (int)(__brev((unsigned)lane) >> 25);
}

__device__ __forceinline__ float2 h2f2(unsigned u){
  union { unsigned u; __half2 h; } cv; cv.u = u;
  return __half22float2(cv.h);
}
__device__ __forceinline__ unsigned f2h2(float re, float im){
  union { unsigned u; __half2 h; } cv;
  cv.h = __float22half2_rn(make_float2(re, im));
  return cv.u;
}

// ======================= Launch 1: fx passes + ctfT + mats ===================
__global__ __launch_bounds__(256) void k_pre1(const float* __restrict__ vol,
                                              const float* __restrict__ imgs,
                                              const float* __restrict__ ctfs,
                                              const float* __restrict__ rotm,
                                              float2* __restrict__ A_T,
                                              float2* __restrict__ AI_T,
                                              float* __restrict__ cfT,
                                              float* __restrict__ mats){
  __shared__ float2 Zbuf[4][128];
  __shared__ float Xr[65][9];
  __shared__ float Xi[65][9];
  int bid = blockIdx.x;
  int t = threadIdx.x, lane = t & 63, w = t >> 6;

  if (bid < 2176){
    bool isimg = (bid >= 2048);
    const float* src = isimg ? imgs : vol;
    float2* dst = isimg ? AI_T : A_T;
    int l0 = (isimg ? (bid - 2048) : bid) * 8;
    int l1 = l0 + 2*w, l2 = l1 + 1;
    float m1a = 1.f, m1b = 1.f, m2a = 1.f, m2b = 1.f;
    if (isimg){
      int y1 = l1 & 127, y2 = y1 + 1;
      int dy1 = y1 - 64, dy2 = y2 - 64;
      int dxa = lane - 64, dxb = lane;
      m1a = (dy1*dy1 + dxa*dxa <= 4096) ? 1.f : 0.f;
      m1b = (dy1*dy1 + dxb*dxb <= 4096) ? 1.f : 0.f;
      m2a = (dy2*dy2 + dxa*dxa <= 4096) ? 1.f : 0.f;
      m2b = (dy2*dy2 + dxb*dxb <= 4096) ? 1.f : 0.f;
    }
    float twr[7], twi[7];
    fft_twiddles(-1.f, lane, twr, twi);
    float Ar = src[l1*DIMN + lane]*m1a,      Ai = src[l2*DIMN + lane]*m2a;
    float Br = src[l1*DIMN + lane + 64]*m1b, Bi = src[l2*DIMN + lane + 64]*m2b;
    wave_fft128(Ar, Ai, Br, Bi, twr, twi, lane);
    int e = bitrev7(lane);
    Zbuf[w][e]   = make_float2(Ar, Ai);
    Zbuf[w][e+1] = make_float2(Br, Bi);
    __syncthreads();
    {
      int k = lane, m = (128 - k) & 127;
      float2 zk = Zbuf[w][k], zm = Zbuf[w][m];
      float s = (k & 1) ? -0.5f : 0.5f;
      int ly1 = 2*w, ly2 = ly1 + 1;
      Xr[k][ly1] = s*(zk.x + zm.x);  Xi[k][ly1] = s*(zk.y - zm.y);
      Xr[k][ly2] = s*(zk.y + zm.y);  Xi[k][ly2] = s*(zm.x - zk.x);
      if (lane == 0){
        float2 z64 = Zbuf[w][64];
        Xr[64][ly1] = z64.x; Xi[64][ly1] = 0.f;
        Xr[64][ly2] = z64.y; Xi[64][ly2] = 0.f;
      }
    }
    __syncthreads();
    int slab = l0 >> 7, y0 = l0 & 127;
    int kk = t >> 2, yo = (t & 3) * 2;
    float4 v = make_float4(Xr[kk][yo], Xi[kk][yo], Xr[kk][yo+1], Xi[kk][yo+1]);
    *(float4*)(dst + (size_t)(slab*KXN + kk)*DIMN + y0 + yo) = v;
    if (t < 4){
      int yo2 = t*2;
      float4 v2 = make_float4(Xr[64][yo2], Xi[64][yo2], Xr[64][yo2+1], Xi[64][yo2+1]);
      *(float4*)(dst + (size_t)(slab*KXN + 64)*DIMN + y0 + yo2) = v2;
    }
  } else if (bid < 2436){
    int idx = (bid - 2176)*256 + t;
    int x = idx % 65; int by = idx / 65; int y = by & 127; int b = by >> 7;
    cfT[((size_t)b*KXN + x)*DIMN + y] = ctfs[idx];
  } else {
    int tid = (bid - 2436)*256 + t;
    if (tid < NBATCH*NOPT){
      int b = tid / NOPT, o = tid - b*NOPT;
      const float* R = rotm + b*9;
      float beta  = acosf(fminf(1.f, fmaxf(-1.f, R[8])));
      float alpha = atan2f(R[5], R[2]);
      float gamma = atan2f(R[7], -R[6]);
      const float DEG = 57.29577951308232f;
      float e0 = alpha*DEG + 3.0f*(float)(o/25      - 2);
      float e1 = beta *DEG + 3.0f*(float)((o/5) % 5 - 2);
      float e2 = gamma*DEG + 3.0f*(float)(o % 5     - 2);
      const float RAD = 0.017453292519943295f;
      float sa, ca, sb, cb, sc, cc;
      sincosf(e0*RAD, &sa, &ca);
      sincosf(e1*RAD, &sb, &cb);
      sincosf(e2*RAD, &sc, &cc);
      float* m = mats + tid*12;
      m[0] = sb*sc;
      m[1] = -sa*cb*sc + ca*cc;
      m[2] = -ca*cb*sc - sa*cc;
      m[3] = -sb*cc;
      m[4] = sa*cb*cc + ca*sc;
      m[5] = ca*cb*cc - sa*sc;
      m[6] = e0; m[7] = e1; m[8] = e2;
    }
  }
}

// ======================= Launch 2: fy passes (vol + img) =====================
__global__ __launch_bounds__(512) void k_pre2(const float2* __restrict__ A_T,
                                              const float2* __restrict__ AI_T,
                                              float2* __restrict__ B_T,
                                              float2* __restrict__ fpT){
  __shared__ float As[64][9], Ai_[64][9], Bs[64][9], Bi_[64][9];
  int bid = blockIdx.x;
  int t = threadIdx.x, lane = t & 63, w = t >> 6;
  float twr[7], twi[7];
  fft_twiddles(-1.f, lane, twr, twi);

  if (bid < 1040){
    int k = bid >> 4, z0 = (bid & 15) * 8;
    int col = (z0 + w)*KXN + k;
    const float2* base = A_T + (size_t)col*DIMN;
    float2 A = base[lane], B = base[lane + 64];
    wave_fft128(A.x, A.y, B.x, B.y, twr, twi, lane);
    int p = bitrev7(lane) >> 1;
    As[p][w] = A.x; Ai_[p][w] = A.y; Bs[p][w] = B.x; Bi_[p][w] = B.y;
    __syncthreads();
    int q = t >> 2, zo = (t & 3) * 2;
    int p2 = (((q & 126) + 64) & 127) >> 1;
    float4 v;
    if (q & 1) v = make_float4(-Bs[p2][zo], -Bi_[p2][zo], -Bs[p2][zo+1], -Bi_[p2][zo+1]);
    else       v = make_float4( As[p2][zo],  Ai_[p2][zo],  As[p2][zo+1],  Ai_[p2][zo+1]);
    *(float4*)(B_T + (size_t)(q*KXN + k)*DIMN + z0 + zo) = v;
  } else {
    int c0 = (bid - 1040) * 8;
    int col = c0 + w;
    const float2* base = AI_T + (size_t)col*DIMN;
    float2 A = base[lane], B = base[lane + 64];
    wave_fft128(A.x, A.y, B.x, B.y, twr, twi, lane);
    int p = bitrev7(lane) >> 1;
    As[p][w] = A.x; Ai_[p][w] = A.y; Bs[p][w] = B.x; Bi_[p][w] = B.y;
    __syncthreads();
    int c = t >> 6, qo = (t & 63) * 2;
    int p2 = ((qo + 64) & 127) >> 1;
    float4 v = make_float4(As[p2][c], Ai_[p2][c], -Bs[p2][c], -Bi_[p2][c]);
    *(float4*)(fpT + (size_t)(c0 + c)*DIMN + qo) = v;
  }
}

// ======================= Launch 3: vol fz pass ===============================
__global__ __launch_bounds__(512) void k_fz(const float2* __restrict__ B_T,
                                            float2* __restrict__ volF){
  __shared__ float As[64][9], Ai_[64][9], Bs[64][9], Bi_[64][9];
  int bid = blockIdx.x;
  int j = bid / 9, grp = bid - j*9;
  int k0 = grp * 8;
  int vw = (grp == 8) ? 1 : 8;
  int t = threadIdx.x, lane = t & 63, w = t >> 6;
  if (w < vw){
    float twr[7], twi[7];
    fft_twiddles(-1.f, lane, twr, twi);
    int col = j*KXN + k0 + w;
    const float2* base = B_T + (size_t)col*DIMN;
    float2 A = base[lane], B = base[lane + 64];
    wave_fft128(A.x, A.y, B.x, B.y, twr, twi, lane);
    int p = bitrev7(lane) >> 1;
    As[p][w] = A.x; Ai_[p][w] = A.y; Bs[p][w] = B.x; Bi_[p][w] = B.y;
  }
  __syncthreads();
  int q = t >> 2, ko = (t & 3) * 2;
  int p2 = (((q & 126) + 64) & 127) >> 1;
  float2* obase = volF + (size_t)(q*DIMN + j)*KXN + k0;
  if (q & 1){
    if (ko < vw)     obase[ko]   = make_float2(-Bs[p2][ko],   -Bi_[p2][ko]);
    if (ko + 1 < vw) obase[ko+1] = make_float2(-Bs[p2][ko+1], -Bi_[p2][ko+1]);
  } else {
    if (ko < vw)     obase[ko]   = make_float2( As[p2][ko],    Ai_[p2][ko]);
    if (ko + 1 < vw) obase[ko+1] = make_float2( As[p2][ko+1],  Ai_[p2][ko+1]);
  }
}

// ------- Fat-texel build (fp16, compact): FATy[z][y][x] = y/z 2x2 at x -------
// entry = {v(z,y,x), v(z,y+1,x), v(z+1,y,x), v(z+1,y+1,x)} as 4 half2 = 16 B.
__global__ __launch_bounds__(256) void k_fat(const float2* __restrict__ volF,
                                             uint4* __restrict__ FATy){
  int idx = blockIdx.x*256 + threadIdx.x;        // over 128*128*65
  int x = idx % 65; int zy = idx / 65; int y = zy & 127; int z = zy >> 7;
  int z1 = min(z+1,127), y1 = min(y+1,127);
  float2 a = volF[((size_t)z *128 + y )*65 + x];
  float2 b = volF[((size_t)z *128 + y1)*65 + x];
  float2 c = volF[((size_t)z1*128 + y )*65 + x];
  float2 d = volF[((size_t)z1*128 + y1)*65 + x];
  FATy[idx] = make_uint4(f2h2(a.x,a.y), f2h2(b.x,b.y), f2h2(c.x,c.y), f2h2(d.x,d.y));
}

// ---- prod element: compact fp16 fat-texel trilinear * ctf, f * conj(P) ------
__device__ __forceinline__ float2 prod_elem(int h, int kx,
                                            float c1z, float c1y, float c1x,
                                            float c2z, float c2y, float c2x,
                                            const uint4* __restrict__ FATy,
                                            const float2* __restrict__ fpc,
                                            const float*  __restrict__ cfc){
  float fyv = (float)(h - 64) * 0.0078125f;
  float fxv = (float)kx * 0.0078125f;
  float cz = fyv*c1z + fxv*c2z;
  float cy = fyv*c1y + fxv*c2y;
  float cx = fyv*c1x + fxv*c2x;
  bool cj = (cx < 0.f);
  if (cj){ cz = -cz; cy = -cy; cx = -cx; }
  float pz = cz*128.f + 64.f;
  float py = cy*128.f + 64.f;
  float px = cx*128.f;
  float fz = floorf(pz), fy = floorf(py), fx = floorf(px);
  int iz = (int)fz, iy = (int)fy, ix = (int)fx;
  float tz = pz - fz, ty = py - fy, tx = px - fx;
  float wz0 = ((unsigned)iz < 128u) ? 1.f - tz : ((iz == -1) ? tz : 0.f);
  float wz1 = ((unsigned)iz < 127u) ? tz : 0.f;
  float wy0 = ((unsigned)iy < 128u) ? 1.f - ty : ((iy == -1) ? ty : 0.f);
  float wy1 = ((unsigned)iy < 127u) ? ty : 0.f;
  float wx0 = ((unsigned)ix < 65u)  ? 1.f - tx : ((ix == -1) ? tx : 0.f);
  float wx1 = ((unsigned)ix < 64u)  ? tx : 0.f;
  int bz = min(max(iz, 0), 127), by = min(max(iy, 0), 127), bx = min(max(ix, 0), 64);
  int bx1 = min(bx + 1, 64);
  const uint4* Fb = FATy + ((size_t)bz*128 + by)*65;
  uint4 F0 = Fb[bx], F1 = Fb[bx1];
  float2 v000 = h2f2(F0.x), v010 = h2f2(F0.y), v100 = h2f2(F0.z), v110 = h2f2(F0.w);
  float2 v001 = h2f2(F1.x), v011 = h2f2(F1.y), v101 = h2f2(F1.z), v111 = h2f2(F1.w);
  float w00 = wz0*wy0, w01 = wz0*wy1, w10 = wz1*wy0, w11 = wz1*wy1;
  float ar = w00*(wx0*v000.x + wx1*v001.x) + w01*(wx0*v010.x + wx1*v011.x)
           + w10*(wx0*v100.x + wx1*v101.x) + w11*(wx0*v110.x + wx1*v111.x);
  float ai = w00*(wx0*v000.y + wx1*v001.y) + w01*(wx0*v010.y + wx1*v011.y)
           + w10*(wx0*v100.y + wx1*v101.y) + w11*(wx0*v110.y + wx1*v111.y);
  if (cj) ai = -ai;
  float ct = cfc[h];
  float Pr = ar*ct, Pi = ai*ct;
  float2 f = fpc[h];
  return make_float2(f.x*Pr + f.y*Pi, f.y*Pr - f.x*Pi);   // f * conj(P)
}

// ---------------- Main: slice + ctf + conj-mult + wave-FFT + argmax ----------
__global__ __launch_bounds__(512, 8) void k_main(const uint4* __restrict__ FATy,
                                                 const float2* __restrict__ fpT,
                                                 const float* __restrict__ cfT,
                                                 const float* __restrict__ mats,
                                                 float* __restrict__ bestv,
                                                 int* __restrict__ besti){
  __shared__ float2 Q[64*65];       // Q[s][kx], normalized, window rows only
  __shared__ float rvw[8];
  __shared__ int   riw[8];

  int t = threadIdx.x, lane = t & 63, g = t >> 6;   // g = 0..7
  int blk = blockIdx.x;
  int b = blk & 7;                  // XCD-pinned batch
  int o = blk >> 3;                 // option

  float twr[7], twi[7];
  fft_twiddles(1.f, lane, twr, twi);

  const float* mp = mats + (size_t)(b*NOPT + o)*12;
  float c1z = mp[0], c1y = mp[1], c1x = mp[2];
  float c2z = mp[3], c2y = mp[4], c2x = mp[5];
  const float2* fp = fpT + (size_t)b*KXN*DIMN;
  const float*  cf = cfT + (size_t)b*KXN*DIMN;

  int e = bitrev7(lane);                         // even
  int slA = (e + 32) & 127;                      // window row for bin e
  bool inwin = (slA < 64);
  const float NRM = 6.103515625e-05f;            // 1/16384

  // ---- Phase A+B: prod columns -> FFT over h -> Q rows ----
#pragma unroll 2
  for (int ci = 0; ci < 8; ++ci){
    int kx = 8*ci + g;                           // <= 63
    const float2* fpc = fp + (size_t)kx*DIMN;
    const float*  cfc = cf + (size_t)kx*DIMN;
    float2 A = prod_elem(lane,      kx, c1z,c1y,c1x, c2z,c2y,c2x, FATy, fpc, cfc);
    float2 B = prod_elem(lane + 64, kx, c1z,c1y,c1x, c2z,c2y,c2x, FATy, fpc, cfc);
    wave_fft128(A.x, A.y, B.x, B.y, twr, twi, lane);
    if (inwin){
      Q[slA*KXN + kx]     = make_float2( A.x*NRM,  A.y*NRM);
      Q[(slA+1)*KXN + kx] = make_float2(-B.x*NRM, -B.y*NRM);
    }
  }
  if (g == 0){
    const int kx = 64;
    const float2* fpc = fp + (size_t)kx*DIMN;
    const float*  cfc = cf + (size_t)kx*DIMN;
    float2 A = prod_elem(lane,      kx, c1z,c1y,c1x, c2z,c2y,c2x, FATy, fpc, cfc);
    float2 B = prod_elem(lane + 64, kx, c1z,c1y,c1x, c2z,c2y,c2x, FATy, fpc, cfc);
    wave_fft128(A.x, A.y, B.x, B.y, twr, twi, lane);
    if (inwin){
      Q[slA*KXN + kx]     = make_float2( A.x*NRM,  A.y*NRM);
      Q[(slA+1)*KXN + kx] = make_float2(-B.x*NRM, -B.y*NRM);
    }
  }
  __syncthreads();

  // ---- Phase C: 32 row-pair FFTs over kx (Hermitian-packed), fused argmax ----
  float bv = -INFINITY; int bi = 0;
  int ra = 64 - lane;
#pragma unroll 1
  for (int pi = 0; pi < 4; ++pi){
    int r1 = (4*g + pi) << 1;
    float2 a1 = Q[r1*KXN + lane];
    float2 a2 = Q[(r1+1)*KXN + lane];
    float2 b1 = Q[r1*KXN + ra];
    float2 b2 = Q[(r1+1)*KXN + ra];
    if (lane == 0){ a1.y = 0.f; a2.y = 0.f; b1.y = 0.f; b2.y = 0.f; }
    else { b1.y = -b1.y; b2.y = -b2.y; }
    float zAr = a1.x - a2.y, zAi = a1.y + a2.x;
    float zBr = b1.x - b2.y, zBi = b1.y + b2.x;
    wave_fft128(zAr, zAi, zBr, zBi, twr, twi, lane);
    if (inwin){
      int i0 = (r1 << 6) + slA;
      if (zAr > bv || (zAr == bv && i0      < bi)){ bv = zAr; bi = i0; }
      if (zAi > bv || (zAi == bv && i0+64   < bi)){ bv = zAi; bi = i0+64; }
      if (zBr > bv || (zBr == bv && i0+1    < bi)){ bv = zBr; bi = i0+1; }
      if (zBi > bv || (zBi == bv && i0+65   < bi)){ bv = zBi; bi = i0+65; }
    }
  }

#pragma unroll
  for (int off = 32; off > 0; off >>= 1){
    float v2 = __shfl_down(bv, off, 64);
    int   i2 = __shfl_down(bi, off, 64);
    if (v2 > bv || (v2 == bv && i2 < bi)){ bv = v2; bi = i2; }
  }
  if (lane == 0){ rvw[g] = bv; riw[g] = bi; }
  __syncthreads();
  if (t == 0){
    float fv = rvw[0]; int fi = riw[0];
#pragma unroll
    for (int wv = 1; wv < 8; ++wv){
      float v2 = rvw[wv]; int i2 = riw[wv];
      if (v2 > fv || (v2 == fv && i2 < fi)){ fv = v2; fi = i2; }
    }
    bestv[b*NOPT + o] = fv; besti[b*NOPT + o] = fi;
  }
}

// ---------------- Final selection / outputs (wave-parallel) ------------------
__global__ __launch_bounds__(64) void k_out(const float* __restrict__ bestv,
                                            const int* __restrict__ besti,
                                            const float* __restrict__ mats,
                                            float* __restrict__ out){
  int b = blockIdx.x, lane = threadIdx.x;
  const float* bvp = bestv + b*NOPT;
  float v1 = (lane      < NOPT) ? bvp[lane]      : -INFINITY;
  float v2 = (lane + 64 < NOPT) ? bvp[lane + 64] : -INFINITY;
  float s1 = (lane      < NOPT) ? v1 : 0.f;
  float s2 = (lane + 64 < NOPT) ? v2 : 0.f;
  float bv; int bo;
  if (v2 > v1){ bv = v2; bo = lane + 64; } else { bv = v1; bo = lane; }
  float sum = s1 + s2;
#pragma unroll
  for (int off = 32; off > 0; off >>= 1){
    float mv = __shfl_down(bv, off, 64);
    int   mo = __shfl_down(bo, off, 64);
    sum += __shfl_down(sum, off, 64);
    if (mv > bv || (mv == bv && mo < bo)){ bv = mv; bo = mo; }
  }
  bv  = __shfl(bv, 0, 64);
  bo  = __shfl(bo, 0, 64);
  sum = __shfl(sum, 0, 64);
  float mean = sum * (1.0f/125.0f);
  float d1 = (lane      < NOPT) ? (v1 - mean) : 0.f;
  float d2 = (lane + 64 < NOPT) ? (v2 - mean) : 0.f;
  float ss = d1*d1 + d2*d2;
#pragma unroll
  for (int off = 32; off > 0; off >>= 1) ss += __shfl_down(ss, off, 64);

  if (lane == 0){
    float stdv = sqrtf(ss * (1.0f/124.0f));
    int wi = besti[b*NOPT + bo];
    int row = (wi >> 6) + 32;
    int col = (wi & 63) + 32;
    out[b] = bv;
    const float* mm = mats + (size_t)(b*NOPT + bo)*12;
    const float RAD = 0.017453292519943295f;
    float sa, ca, sb, cb, sc, cc;
    sincosf(mm[6]*RAD, &sa, &ca);
    sincosf(mm[7]*RAD, &sb, &cb);
    sincosf(mm[8]*RAD, &sc, &cc);
    float* R = out + 8 + b*9;
    R[0] = ca*cb*cc - sa*sc;  R[1] = -ca*cb*sc - sa*cc;  R[2] = ca*sb;
    R[3] = sa*cb*cc + ca*sc;  R[4] = -sa*cb*sc + ca*cc;  R[5] = sa*sb;
    R[6] = -sb*cc;            R[7] = sb*sc;              R[8] = cb;
    out[80 + b*2 + 0] = -((float)col - 64.f) * 1.5f;
    out[80 + b*2 + 1] = -((float)row - 64.f) * 1.5f;
    float z = (bv - mean) / ((stdv + 1e-6f) * 1.4142135623730951f);
    out[96 + b] = 0.5f*(1.f + erff(z));
  }
}

extern "C" void kernel_launch(void* const* d_in, const int* in_sizes, int n_in,
                              void* d_out, int out_size, void* d_ws, size_t ws_size,
                              hipStream_t stream){
  (void)in_sizes; (void)n_in; (void)out_size; (void)ws_size;
  const float* vol  = (const float*)d_in[0];
  const float* imgs = (const float*)d_in[1];
  const float* ctfs = (const float*)d_in[2];
  const float* rotm = (const float*)d_in[3];
  float* out = (float*)d_out;

  uint4* FATy  = (uint4*)d_ws;                          // 128*128*65 * 16 B = 17 MB
  float2* bufA  = (float2*)(FATy + (size_t)DIMN*DIMN*KXN);
  float2* bufB  = bufA + (size_t)DIMN*DIMN*KXN;         // 128*128*65 cplx
  float2* imgT  = bufB + (size_t)DIMN*DIMN*KXN;         // 8*65*128 cplx
  float2* fpT   = imgT + (size_t)NBATCH*KXN*DIMN;       // 8*65*128 cplx
  float*  cfT   = (float*)(fpT + (size_t)NBATCH*KXN*DIMN);   // 8*65*128 f32
  float*  mats  = cfT + (size_t)NBATCH*KXN*DIMN;        // 1000*12 f32
  float*  bestv = mats + 12000;                         // 1000 f32
  int*    besti = (int*)(bestv + 1000);                 // 1000 i32

  k_pre1<<<2440, 256, 0, stream>>>(vol, imgs, ctfs, rotm, bufA, imgT, cfT, mats);
  k_pre2<<<1105, 512, 0, stream>>>(bufA, imgT, bufB, fpT);
  k_fz<<<1152, 512, 0, stream>>>(bufB, bufA);           // bufA == vol_rfft
  k_fat<<<(DIMN*DIMN*KXN)/256, 256, 0, stream>>>(bufA, FATy);
  k_main<<<NBATCH*NOPT, 512, 0, stream>>>(FATy, fpT, cfT, mats, bestv, besti);
  k_out<<<NBATCH, 64, 0, stream>>>(bestv, besti, mats, out);
}

// Round 10
// 103.736 us; speedup vs baseline: 1.1257x; 1.1257x over previous
//
#include <hip/hip_runtime.h>
#include <hip/hip_fp16.h>
#include <math.h>

#define DIMN 128
#define KXN  65
#define NBATCH 8
#define NOPT 125

// ============ wave-level 128-point FFT (radix-2 DIF, 2 points/lane) ==========
__device__ __forceinline__ void fft_twiddles(float sigma, int lane,
                                             float* twr, float* twi){
  const float W = 0.04908738521234052f;   // 2*pi/128
  float s, c;
  sincosf(sigma * W * (float)lane, &s, &c);
  twr[0] = c; twi[0] = s;
#pragma unroll
  for (int st = 1; st <= 6; ++st){
    int off = 64 >> st;
    int m = (lane & (off - 1)) << st;
    sincosf(sigma * W * (float)m, &s, &c);
    bool hi = (lane & off) != 0;
    twr[st] = hi ? c : 1.f;
    twi[st] = hi ? s : 0.f;
  }
}

__device__ __forceinline__ void wave_fft128(float& Ar, float& Ai, float& Br, float& Bi,
                                            const float* twr, const float* twi, int lane){
  {
    float dr = Ar - Br, di = Ai - Bi;
    Ar += Br; Ai += Bi;
    float nr = dr*twr[0] - di*twi[0];
    Bi = dr*twi[0] + di*twr[0];
    Br = nr;
  }
#pragma unroll
  for (int s = 1; s <= 6; ++s){
    int off = 64 >> s;
    float sgn = (lane & off) ? -1.f : 1.f;
    float pr = __shfl_xor(Ar, off, 64);
    float pi = __shfl_xor(Ai, off, 64);
    float dr = fmaf(Ar, sgn, pr);
    float di = fmaf(Ai, sgn, pi);
    Ar = dr*twr[s] - di*twi[s];
    Ai = dr*twi[s] + di*twr[s];
    pr = __shfl_xor(Br, off, 64);
    pi = __shfl_xor(Bi, off, 64);
    dr = fmaf(Br, sgn, pr);
    di = fmaf(Bi, sgn, pi);
    Br = dr*twr[s] - di*twi[s];
    Bi = dr*twi[s] + di*twr[s];
  }
}

__device__ __forceinline__ int bitrev7(int lane){
  return (int)(__brev((unsigned)lane) >> 25);
}

__device__ __forceinline__ float2 h2f2(unsigned u){
  union { unsigned u; __half2 h; } cv; cv.u = u;
  return __half22float2(cv.h);
}
__device__ __forceinline__ unsigned f2h2(float re, float im){
  union { unsigned u; __half2 h; } cv;
  cv.h = __float22half2_rn(make_float2(re, im));
  return cv.u;
}

// ======================= Launch 1: fx passes + ctfT + mats ===================
__global__ __launch_bounds__(256) void k_pre1(const float* __restrict__ vol,
                                              const float* __restrict__ imgs,
                                              const float* __restrict__ ctfs,
                                              const float* __restrict__ rotm,
                                              float2* __restrict__ A_T,
                                              float2* __restrict__ AI_T,
                                              float* __restrict__ cfT,
                                              float* __restrict__ mats){
  __shared__ float2 Zbuf[4][128];
  __shared__ float Xr[65][9];
  __shared__ float Xi[65][9];
  int bid = blockIdx.x;
  int t = threadIdx.x, lane = t & 63, w = t >> 6;

  if (bid < 2176){
    bool isimg = (bid >= 2048);
    const float* src = isimg ? imgs : vol;
    float2* dst = isimg ? AI_T : A_T;
    int l0 = (isimg ? (bid - 2048) : bid) * 8;
    int l1 = l0 + 2*w, l2 = l1 + 1;
    float m1a = 1.f, m1b = 1.f, m2a = 1.f, m2b = 1.f;
    if (isimg){
      int y1 = l1 & 127, y2 = y1 + 1;
      int dy1 = y1 - 64, dy2 = y2 - 64;
      int dxa = lane - 64, dxb = lane;
      m1a = (dy1*dy1 + dxa*dxa <= 4096) ? 1.f : 0.f;
      m1b = (dy1*dy1 + dxb*dxb <= 4096) ? 1.f : 0.f;
      m2a = (dy2*dy2 + dxa*dxa <= 4096) ? 1.f : 0.f;
      m2b = (dy2*dy2 + dxb*dxb <= 4096) ? 1.f : 0.f;
    }
    float twr[7], twi[7];
    fft_twiddles(-1.f, lane, twr, twi);
    float Ar = src[l1*DIMN + lane]*m1a,      Ai = src[l2*DIMN + lane]*m2a;
    float Br = src[l1*DIMN + lane + 64]*m1b, Bi = src[l2*DIMN + lane + 64]*m2b;
    wave_fft128(Ar, Ai, Br, Bi, twr, twi, lane);
    int e = bitrev7(lane);
    Zbuf[w][e]   = make_float2(Ar, Ai);
    Zbuf[w][e+1] = make_float2(Br, Bi);
    __syncthreads();
    {
      int k = lane, m = (128 - k) & 127;
      float2 zk = Zbuf[w][k], zm = Zbuf[w][m];
      float s = (k & 1) ? -0.5f : 0.5f;
      int ly1 = 2*w, ly2 = ly1 + 1;
      Xr[k][ly1] = s*(zk.x + zm.x);  Xi[k][ly1] = s*(zk.y - zm.y);
      Xr[k][ly2] = s*(zk.y + zm.y);  Xi[k][ly2] = s*(zm.x - zk.x);
      if (lane == 0){
        float2 z64 = Zbuf[w][64];
        Xr[64][ly1] = z64.x; Xi[64][ly1] = 0.f;
        Xr[64][ly2] = z64.y; Xi[64][ly2] = 0.f;
      }
    }
    __syncthreads();
    int slab = l0 >> 7, y0 = l0 & 127;
    int kk = t >> 2, yo = (t & 3) * 2;
    float4 v = make_float4(Xr[kk][yo], Xi[kk][yo], Xr[kk][yo+1], Xi[kk][yo+1]);
    *(float4*)(dst + (size_t)(slab*KXN + kk)*DIMN + y0 + yo) = v;
    if (t < 4){
      int yo2 = t*2;
      float4 v2 = make_float4(Xr[64][yo2], Xi[64][yo2], Xr[64][yo2+1], Xi[64][yo2+1]);
      *(float4*)(dst + (size_t)(slab*KXN + 64)*DIMN + y0 + yo2) = v2;
    }
  } else if (bid < 2436){
    int idx = (bid - 2176)*256 + t;
    int x = idx % 65; int by = idx / 65; int y = by & 127; int b = by >> 7;
    cfT[((size_t)b*KXN + x)*DIMN + y] = ctfs[idx];
  } else {
    int tid = (bid - 2436)*256 + t;
    if (tid < NBATCH*NOPT){
      int b = tid / NOPT, o = tid - b*NOPT;
      const float* R = rotm + b*9;
      float beta  = acosf(fminf(1.f, fmaxf(-1.f, R[8])));
      float alpha = atan2f(R[5], R[2]);
      float gamma = atan2f(R[7], -R[6]);
      const float DEG = 57.29577951308232f;
      float e0 = alpha*DEG + 3.0f*(float)(o/25      - 2);
      float e1 = beta *DEG + 3.0f*(float)((o/5) % 5 - 2);
      float e2 = gamma*DEG + 3.0f*(float)(o % 5     - 2);
      const float RAD = 0.017453292519943295f;
      float sa, ca, sb, cb, sc, cc;
      sincosf(e0*RAD, &sa, &ca);
      sincosf(e1*RAD, &sb, &cb);
      sincosf(e2*RAD, &sc, &cc);
      float* m = mats + tid*12;
      m[0] = sb*sc;
      m[1] = -sa*cb*sc + ca*cc;
      m[2] = -ca*cb*sc - sa*cc;
      m[3] = -sb*cc;
      m[4] = sa*cb*cc + ca*sc;
      m[5] = ca*cb*cc - sa*sc;
      m[6] = e0; m[7] = e1; m[8] = e2;
    }
  }
}

// ======================= Launch 2: fy passes (vol + img) =====================
__global__ __launch_bounds__(512) void k_pre2(const float2* __restrict__ A_T,
                                              const float2* __restrict__ AI_T,
                                              float2* __restrict__ B_T,
                                              float2* __restrict__ fpT){
  __shared__ float As[64][9], Ai_[64][9], Bs[64][9], Bi_[64][9];
  int bid = blockIdx.x;
  int t = threadIdx.x, lane = t & 63, w = t >> 6;
  float twr[7], twi[7];
  fft_twiddles(-1.f, lane, twr, twi);

  if (bid < 1040){
    int k = bid >> 4, z0 = (bid & 15) * 8;
    int col = (z0 + w)*KXN + k;
    const float2* base = A_T + (size_t)col*DIMN;
    float2 A = base[lane], B = base[lane + 64];
    wave_fft128(A.x, A.y, B.x, B.y, twr, twi, lane);
    int p = bitrev7(lane) >> 1;
    As[p][w] = A.x; Ai_[p][w] = A.y; Bs[p][w] = B.x; Bi_[p][w] = B.y;
    __syncthreads();
    int q = t >> 2, zo = (t & 3) * 2;
    int p2 = (((q & 126) + 64) & 127) >> 1;
    float4 v;
    if (q & 1) v = make_float4(-Bs[p2][zo], -Bi_[p2][zo], -Bs[p2][zo+1], -Bi_[p2][zo+1]);
    else       v = make_float4( As[p2][zo],  Ai_[p2][zo],  As[p2][zo+1],  Ai_[p2][zo+1]);
    *(float4*)(B_T + (size_t)(q*KXN + k)*DIMN + z0 + zo) = v;
  } else {
    int c0 = (bid - 1040) * 8;
    int col = c0 + w;
    const float2* base = AI_T + (size_t)col*DIMN;
    float2 A = base[lane], B = base[lane + 64];
    wave_fft128(A.x, A.y, B.x, B.y, twr, twi, lane);
    int p = bitrev7(lane) >> 1;
    As[p][w] = A.x; Ai_[p][w] = A.y; Bs[p][w] = B.x; Bi_[p][w] = B.y;
    __syncthreads();
    int c = t >> 6, qo = (t & 63) * 2;
    int p2 = ((qo + 64) & 127) >> 1;
    float4 v = make_float4(As[p2][c], Ai_[p2][c], -Bs[p2][c], -Bi_[p2][c]);
    *(float4*)(fpT + (size_t)(c0 + c)*DIMN + qo) = v;
  }
}

// ======================= Launch 3: vol fz pass ===============================
__global__ __launch_bounds__(512) void k_fz(const float2* __restrict__ B_T,
                                            float2* __restrict__ volF){
  __shared__ float As[64][9], Ai_[64][9], Bs[64][9], Bi_[64][9];
  int bid = blockIdx.x;
  int j = bid / 9, grp = bid - j*9;
  int k0 = grp * 8;
  int vw = (grp == 8) ? 1 : 8;
  int t = threadIdx.x, lane = t & 63, w = t >> 6;
  if (w < vw){
    float twr[7], twi[7];
    fft_twiddles(-1.f, lane, twr, twi);
    int col = j*KXN + k0 + w;
    const float2* base = B_T + (size_t)col*DIMN;
    float2 A = base[lane], B = base[lane + 64];
    wave_fft128(A.x, A.y, B.x, B.y, twr, twi, lane);
    int p = bitrev7(lane) >> 1;
    As[p][w] = A.x; Ai_[p][w] = A.y; Bs[p][w] = B.x; Bi_[p][w] = B.y;
  }
  __syncthreads();
  int q = t >> 2, ko = (t & 3) * 2;
  int p2 = (((q & 126) + 64) & 127) >> 1;
  float2* obase = volF + (size_t)(q*DIMN + j)*KXN + k0;
  if (q & 1){
    if (ko < vw)     obase[ko]   = make_float2(-Bs[p2][ko],   -Bi_[p2][ko]);
    if (ko + 1 < vw) obase[ko+1] = make_float2(-Bs[p2][ko+1], -Bi_[p2][ko+1]);
  } else {
    if (ko < vw)     obase[ko]   = make_float2( As[p2][ko],    Ai_[p2][ko]);
    if (ko + 1 < vw) obase[ko+1] = make_float2( As[p2][ko+1],  Ai_[p2][ko+1]);
  }
}

// ------- Fat-texel build (fp16, compact): FATy[z][y][x] = y/z 2x2 at x -------
// entry = {v(z,y,x), v(z,y+1,x), v(z+1,y,x), v(z+1,y+1,x)} as 4 half2 = 16 B.
__global__ __launch_bounds__(256) void k_fat(const float2* __restrict__ volF,
                                             uint4* __restrict__ FATy){
  int idx = blockIdx.x*256 + threadIdx.x;        // over 128*128*65
  int x = idx % 65; int zy = idx / 65; int y = zy & 127; int z = zy >> 7;
  int z1 = min(z+1,127), y1 = min(y+1,127);
  float2 a = volF[((size_t)z *128 + y )*65 + x];
  float2 b = volF[((size_t)z *128 + y1)*65 + x];
  float2 c = volF[((size_t)z1*128 + y )*65 + x];
  float2 d = volF[((size_t)z1*128 + y1)*65 + x];
  FATy[idx] = make_uint4(f2h2(a.x,a.y), f2h2(b.x,b.y), f2h2(c.x,c.y), f2h2(d.x,d.y));
}

// ---- prod element: compact fp16 fat-texel trilinear * ctf, f * conj(P) ------
__device__ __forceinline__ float2 prod_elem(int h, int kx,
                                            float c1z, float c1y, float c1x,
                                            float c2z, float c2y, float c2x,
                                            const uint4* __restrict__ FATy,
                                            const float2* __restrict__ fpc,
                                            const float*  __restrict__ cfc){
  float fyv = (float)(h - 64) * 0.0078125f;
  float fxv = (float)kx * 0.0078125f;
  float cz = fyv*c1z + fxv*c2z;
  float cy = fyv*c1y + fxv*c2y;
  float cx = fyv*c1x + fxv*c2x;
  bool cj = (cx < 0.f);
  if (cj){ cz = -cz; cy = -cy; cx = -cx; }
  float pz = cz*128.f + 64.f;
  float py = cy*128.f + 64.f;
  float px = cx*128.f;
  float fz = floorf(pz), fy = floorf(py), fx = floorf(px);
  int iz = (int)fz, iy = (int)fy, ix = (int)fx;
  float tz = pz - fz, ty = py - fy, tx = px - fx;
  float wz0 = ((unsigned)iz < 128u) ? 1.f - tz : ((iz == -1) ? tz : 0.f);
  float wz1 = ((unsigned)iz < 127u) ? tz : 0.f;
  float wy0 = ((unsigned)iy < 128u) ? 1.f - ty : ((iy == -1) ? ty : 0.f);
  float wy1 = ((unsigned)iy < 127u) ? ty : 0.f;
  float wx0 = ((unsigned)ix < 65u)  ? 1.f - tx : ((ix == -1) ? tx : 0.f);
  float wx1 = ((unsigned)ix < 64u)  ? tx : 0.f;
  int bz = min(max(iz, 0), 127), by = min(max(iy, 0), 127), bx = min(max(ix, 0), 64);
  int bx1 = min(bx + 1, 64);
  const uint4* Fb = FATy + ((size_t)bz*128 + by)*65;
  uint4 F0 = Fb[bx], F1 = Fb[bx1];
  float2 v000 = h2f2(F0.x), v010 = h2f2(F0.y), v100 = h2f2(F0.z), v110 = h2f2(F0.w);
  float2 v001 = h2f2(F1.x), v011 = h2f2(F1.y), v101 = h2f2(F1.z), v111 = h2f2(F1.w);
  float w00 = wz0*wy0, w01 = wz0*wy1, w10 = wz1*wy0, w11 = wz1*wy1;
  float ar = w00*(wx0*v000.x + wx1*v001.x) + w01*(wx0*v010.x + wx1*v011.x)
           + w10*(wx0*v100.x + wx1*v101.x) + w11*(wx0*v110.x + wx1*v111.x);
  float ai = w00*(wx0*v000.y + wx1*v001.y) + w01*(wx0*v010.y + wx1*v011.y)
           + w10*(wx0*v100.y + wx1*v101.y) + w11*(wx0*v110.y + wx1*v111.y);
  if (cj) ai = -ai;
  float ct = cfc[h];
  float Pr = ar*ct, Pi = ai*ct;
  float2 f = fpc[h];
  return make_float2(f.x*Pr + f.y*Pi, f.y*Pr - f.x*Pi);   // f * conj(P)
}

// ---------------- Main: slice + ctf + conj-mult + wave-FFT + argmax ----------
__global__ __launch_bounds__(512, 8) void k_main(const uint4* __restrict__ FATy,
                                                 const float2* __restrict__ fpT,
                                                 const float* __restrict__ cfT,
                                                 const float* __restrict__ mats,
                                                 float* __restrict__ bestv,
                                                 int* __restrict__ besti){
  __shared__ float2 Q[64*65];       // Q[s][kx], normalized, window rows only
  __shared__ float rvw[8];
  __shared__ int   riw[8];

  int t = threadIdx.x, lane = t & 63, g = t >> 6;   // g = 0..7
  int blk = blockIdx.x;
  int b = blk & 7;                  // XCD-pinned batch
  int o = blk >> 3;                 // option

  float twr[7], twi[7];
  fft_twiddles(1.f, lane, twr, twi);

  const float* mp = mats + (size_t)(b*NOPT + o)*12;
  float c1z = mp[0], c1y = mp[1], c1x = mp[2];
  float c2z = mp[3], c2y = mp[4], c2x = mp[5];
  const float2* fp = fpT + (size_t)b*KXN*DIMN;
  const float*  cf = cfT + (size_t)b*KXN*DIMN;

  int e = bitrev7(lane);                         // even
  int slA = (e + 32) & 127;                      // window row for bin e
  bool inwin = (slA < 64);
  const float NRM = 6.103515625e-05f;            // 1/16384

  // ---- Phase A+B: prod columns -> FFT over h -> Q rows ----
#pragma unroll 1
  for (int ci = 0; ci < 8; ++ci){
    int kx = 8*ci + g;                           // <= 63
    const float2* fpc = fp + (size_t)kx*DIMN;
    const float*  cfc = cf + (size_t)kx*DIMN;
    float2 A = prod_elem(lane,      kx, c1z,c1y,c1x, c2z,c2y,c2x, FATy, fpc, cfc);
    float2 B = prod_elem(lane + 64, kx, c1z,c1y,c1x, c2z,c2y,c2x, FATy, fpc, cfc);
    wave_fft128(A.x, A.y, B.x, B.y, twr, twi, lane);
    if (inwin){
      Q[slA*KXN + kx]     = make_float2( A.x*NRM,  A.y*NRM);
      Q[(slA+1)*KXN + kx] = make_float2(-B.x*NRM, -B.y*NRM);
    }
  }
  if (g == 0){
    const int kx = 64;
    const float2* fpc = fp + (size_t)kx*DIMN;
    const float*  cfc = cf + (size_t)kx*DIMN;
    float2 A = prod_elem(lane,      kx, c1z,c1y,c1x, c2z,c2y,c2x, FATy, fpc, cfc);
    float2 B = prod_elem(lane + 64, kx, c1z,c1y,c1x, c2z,c2y,c2x, FATy, fpc, cfc);
    wave_fft128(A.x, A.y, B.x, B.y, twr, twi, lane);
    if (inwin){
      Q[slA*KXN + kx]     = make_float2( A.x*NRM,  A.y*NRM);
      Q[(slA+1)*KXN + kx] = make_float2(-B.x*NRM, -B.y*NRM);
    }
  }
  __syncthreads();

  // ---- Phase C: 32 row-pair FFTs over kx (Hermitian-packed), fused argmax ----
  float bv = -INFINITY; int bi = 0;
  int ra = 64 - lane;
#pragma unroll 1
  for (int pi = 0; pi < 4; ++pi){
    int r1 = (4*g + pi) << 1;
    float2 a1 = Q[r1*KXN + lane];
    float2 a2 = Q[(r1+1)*KXN + lane];
    float2 b1 = Q[r1*KXN + ra];
    float2 b2 = Q[(r1+1)*KXN + ra];
    if (lane == 0){ a1.y = 0.f; a2.y = 0.f; b1.y = 0.f; b2.y = 0.f; }
    else { b1.y = -b1.y; b2.y = -b2.y; }
    float zAr = a1.x - a2.y, zAi = a1.y + a2.x;
    float zBr = b1.x - b2.y, zBi = b1.y + b2.x;
    wave_fft128(zAr, zAi, zBr, zBi, twr, twi, lane);
    if (inwin){
      int i0 = (r1 << 6) + slA;
      if (zAr > bv || (zAr == bv && i0      < bi)){ bv = zAr; bi = i0; }
      if (zAi > bv || (zAi == bv && i0+64   < bi)){ bv = zAi; bi = i0+64; }
      if (zBr > bv || (zBr == bv && i0+1    < bi)){ bv = zBr; bi = i0+1; }
      if (zBi > bv || (zBi == bv && i0+65   < bi)){ bv = zBi; bi = i0+65; }
    }
  }

#pragma unroll
  for (int off = 32; off > 0; off >>= 1){
    float v2 = __shfl_down(bv, off, 64);
    int   i2 = __shfl_down(bi, off, 64);
    if (v2 > bv || (v2 == bv && i2 < bi)){ bv = v2; bi = i2; }
  }
  if (lane == 0){ rvw[g] = bv; riw[g] = bi; }
  __syncthreads();
  if (t == 0){
    float fv = rvw[0]; int fi = riw[0];
#pragma unroll
    for (int wv = 1; wv < 8; ++wv){
      float v2 = rvw[wv]; int i2 = riw[wv];
      if (v2 > fv || (v2 == fv && i2 < fi)){ fv = v2; fi = i2; }
    }
    bestv[b*NOPT + o] = fv; besti[b*NOPT + o] = fi;
  }
}

// ---------------- Final selection / outputs (wave-parallel) ------------------
__global__ __launch_bounds__(64) void k_out(const float* __restrict__ bestv,
                                            const int* __restrict__ besti,
                                            const float* __restrict__ mats,
                                            float* __restrict__ out){
  int b = blockIdx.x, lane = threadIdx.x;
  const float* bvp = bestv + b*NOPT;
  float v1 = (lane      < NOPT) ? bvp[lane]      : -INFINITY;
  float v2 = (lane + 64 < NOPT) ? bvp[lane + 64] : -INFINITY;
  float s1 = (lane      < NOPT) ? v1 : 0.f;
  float s2 = (lane + 64 < NOPT) ? v2 : 0.f;
  float bv; int bo;
  if (v2 > v1){ bv = v2; bo = lane + 64; } else { bv = v1; bo = lane; }
  float sum = s1 + s2;
#pragma unroll
  for (int off = 32; off > 0; off >>= 1){
    float mv = __shfl_down(bv, off, 64);
    int   mo = __shfl_down(bo, off, 64);
    sum += __shfl_down(sum, off, 64);
    if (mv > bv || (mv == bv && mo < bo)){ bv = mv; bo = mo; }
  }
  bv  = __shfl(bv, 0, 64);
  bo  = __shfl(bo, 0, 64);
  sum = __shfl(sum, 0, 64);
  float mean = sum * (1.0f/125.0f);
  float d1 = (lane      < NOPT) ? (v1 - mean) : 0.f;
  float d2 = (lane + 64 < NOPT) ? (v2 - mean) : 0.f;
  float ss = d1*d1 + d2*d2;
#pragma unroll
  for (int off = 32; off > 0; off >>= 1) ss += __shfl_down(ss, off, 64);

  if (lane == 0){
    float stdv = sqrtf(ss * (1.0f/124.0f));
    int wi = besti[b*NOPT + bo];
    int row = (wi >> 6) + 32;
    int col = (wi & 63) + 32;
    out[b] = bv;
    const float* mm = mats + (size_t)(b*NOPT + bo)*12;
    const float RAD = 0.017453292519943295f;
    float sa, ca, sb, cb, sc, cc;
    sincosf(mm[6]*RAD, &sa, &ca);
    sincosf(mm[7]*RAD, &sb, &cb);
    sincosf(mm[8]*RAD, &sc, &cc);
    float* R = out + 8 + b*9;
    R[0] = ca*cb*cc - sa*sc;  R[1] = -ca*cb*sc - sa*cc;  R[2] = ca*sb;
    R[3] = sa*cb*cc + ca*sc;  R[4] = -sa*cb*sc + ca*cc;  R[5] = sa*sb;
    R[6] = -sb*cc;            R[7] = sb*sc;              R[8] = cb;
    out[80 + b*2 + 0] = -((float)col - 64.f) * 1.5f;
    out[80 + b*2 + 1] = -((float)row - 64.f) * 1.5f;
    float z = (bv - mean) / ((stdv + 1e-6f) * 1.4142135623730951f);
    out[96 + b] = 0.5f*(1.f + erff(z));
  }
}

extern "C" void kernel_launch(void* const* d_in, const int* in_sizes, int n_in,
                              void* d_out, int out_size, void* d_ws, size_t ws_size,
                              hipStream_t stream){
  (void)in_sizes; (void)n_in; (void)out_size; (void)ws_size;
  const float* vol  = (const float*)d_in[0];
  const float* imgs = (const float*)d_in[1];
  const float* ctfs = (const float*)d_in[2];
  const float* rotm = (const float*)d_in[3];
  float* out = (float*)d_out;

  uint4* FATy  = (uint4*)d_ws;                          // 128*128*65 * 16 B = 17 MB
  float2* bufA  = (float2*)(FATy + (size_t)DIMN*DIMN*KXN);
  float2* bufB  = bufA + (size_t)DIMN*DIMN*KXN;         // 128*128*65 cplx
  float2* imgT  = bufB + (size_t)DIMN*DIMN*KXN;         // 8*65*128 cplx
  float2* fpT   = imgT + (size_t)NBATCH*KXN*DIMN;       // 8*65*128 cplx
  float*  cfT   = (float*)(fpT + (size_t)NBATCH*KXN*DIMN);   // 8*65*128 f32
  float*  mats  = cfT + (size_t)NBATCH*KXN*DIMN;        // 1000*12 f32
  float*  bestv = mats + 12000;                         // 1000 f32
  int*    besti = (int*)(bestv + 1000);                 // 1000 i32

  k_pre1<<<2440, 256, 0, stream>>>(vol, imgs, ctfs, rotm, bufA, imgT, cfT, mats);
  k_pre2<<<1105, 512, 0, stream>>>(bufA, imgT, bufB, fpT);
  k_fz<<<1152, 512, 0, stream>>>(bufB, bufA);           // bufA == vol_rfft
  k_fat<<<(DIMN*DIMN*KXN)/256, 256, 0, stream>>>(bufA, FATy);
  k_main<<<NBATCH*NOPT, 512, 0, stream>>>(FATy, fpT, cfT, mats, bestv, besti);
  k_out<<<NBATCH, 64, 0, stream>>>(bestv, besti, mats, out);
}